// Round 1
// baseline (74.406 us; speedup 1.0000x reference)
//
#include <hip/hip_runtime.h>

// HEAQNetwork via full Heisenberg (Pauli) propagation — zero state evolution
// (derivation verified R6, absmax 0.25). R9: split-pair layout — thread t
// handles elements t and t+H (H=B/2) instead of 2t,2t+1. Both 16B input
// loads are now lane-contiguous (perfectly coalesced, 1 cacheline segment
// per instruction) instead of 32B-lane-strided; output becomes two coalesced
// 8B float2 stores. Math body unchanged from R8b.

typedef float vfloat4 __attribute__((ext_vector_type(4)));
typedef float vfloat2 __attribute__((ext_vector_type(2)));

__device__ __forceinline__ float rdlane(float x, int l) {
    return __int_as_float(__builtin_amdgcn_readlane(__float_as_int(x), l));
}

__global__ __launch_bounds__(256) void heaq_kernel(
    const vfloat4* __restrict__ x4,
    const float*  __restrict__ w_input,
    const float*  __restrict__ weights,
    const float*  __restrict__ w_output,
    vfloat2*      __restrict__ out2,
    int H)   // H = B/2 threads
{
    const int lane = threadIdx.x & 63;

    // full-angle sincos of the 12 batch-uniform weights via lanes 0..11
    const float K2 = 0.15915494309189535f;  // 1/(2*pi)
    float wv  = weights[lane < 12 ? lane : 11];
    float rev = __builtin_amdgcn_fractf(wv * K2);
    float sn  = __builtin_amdgcn_sinf(rev);
    float cn  = __builtin_amdgcn_cosf(rev);

    const float sw00 = rdlane(sn, 0), cw00 = rdlane(cn, 0);
    const float sw01 = rdlane(sn, 1), cw01 = rdlane(cn, 1);
    const float sw02 = rdlane(sn, 2), cw02 = rdlane(cn, 2);
    const float sw03 = rdlane(sn, 3);
    const float sB0  = rdlane(sn, 4), cB0  = rdlane(cn, 4);
    const float sB1  = rdlane(sn, 5), cB1  = rdlane(cn, 5);
    const float sB2  = rdlane(sn, 6), cB2  = rdlane(cn, 6);
    const float sC0  = rdlane(sn, 8), cC0  = rdlane(cn, 8);
    const float sC1  = rdlane(sn, 9), cC1  = rdlane(cn, 9);

    const int b = blockIdx.x * 256 + threadIdx.x;
    if (b >= H) return;

    const float wi0 = w_input[0], wi1 = w_input[1];
    const float wi2 = w_input[2], wi3 = w_input[3];
    const float hw0 = 0.5f * w_output[0], hw1 = 0.5f * w_output[1];

    // split pair: elements b and b+H — both loads lane-contiguous
    const vfloat4 xva = __builtin_nontemporal_load(&x4[b]);
    const vfloat4 xvb = __builtin_nontemporal_load(&x4[b + H]);

    float zo[2][2];

#pragma unroll
    for (int e = 0; e < 2; ++e) {
        const vfloat4 xv = e ? xvb : xva;
        const float us[4] = {xv.x * wi0, xv.y * wi1, xv.z * wi2, xv.w * wi3};
        float ca[4], sa[4];
#pragma unroll
        for (int q = 0; q < 4; ++q) {
            float u = us[q];
            float r = __builtin_amdgcn_rsqf(__builtin_fmaf(u, u, 1.0f));
            ca[q] = r;
            sa[q] = u * r;
        }

        // Bloch vectors of chi_q = RY(w0q) RX(a_q) |0>
        const float s0x = sw00 * ca[0], s0y = -sa[0], s0z = cw00 * ca[0];
        const float s1x = sw01 * ca[1], s1y = -sa[1], s1z = cw01 * ca[1];
        const float s2x = sw02 * ca[2], s2y = -sa[2], s2z = cw02 * ca[2];
        const float s3x = sw03 * ca[3];

        // D rows (layer-2 conjugation) and n,p (layer 3)
        const float ax = cB0, ay = sB0 * sa[0], az = sB0 * ca[0];
        const float           by = ca[0],       bz = -sa[0];
        const float dx = -sB0, dy = cB0 * sa[0], dz = cB0 * ca[0];
        const float ex = cB1, ey = sB1 * sa[1], ez = sB1 * ca[1];
        const float           fy = ca[1],       fz = -sa[1];
        const float gx = -sB1, gy = cB1 * sa[1], gz = cB1 * ca[1];
        const float hx = cB2, hy = sB2 * sa[2], hz = sB2 * ca[2];
        const float nx = -sC0, ny = cC0 * sa[0], nz = cC0 * ca[0];
        const float px = -sC1, py = cC1 * sa[1], pz = cC1 * ca[1];

        // shared precomputes
        const float t01   = s0z * s1x;
        const float t0z1y = s0z * s1y;
        const float t0z1z = s0z * s1z;
        const float m1 = s2y * s3x, m2 = s2x * s3x, m3 = s2z * s3x;
        const float RCh = __builtin_fmaf(hy, m1, hz * s2z);
        const float RDh = hx * m2;
        const float hx3 = hx * s3x;
        const float q1t = __builtin_fmaf(hz, s2y, -(hy * m3));

        const float Aa = __builtin_fmaf(ax, s0x, ay * s0y);
        const float Ba = __builtin_fmaf(ax, s0y, -(ay * s0x));
        const float Ab = by * s0y;
        const float Bb = -(by * s0x);
        const float Ad = __builtin_fmaf(dx, s0x, dy * s0y);
        const float Bd = __builtin_fmaf(dx, s0y, -(dy * s0x));

        // z0 = E01(u, e) + nz * E0(d),  u = nx*a + ny*b
        const float ux = nx * ax;
        const float uy = __builtin_fmaf(nx, ay, ny * by);
        const float uz = __builtin_fmaf(nx, az, ny * bz);
        const float Au = __builtin_fmaf(ux, s0x, uy * s0y);
        const float Bu = __builtin_fmaf(ux, s0y, -(uy * s0x));
        const float E01u = (ex * s2x) * __builtin_fmaf(uz, t01, Au)
                         + (ey * s2x) * __builtin_fmaf(Bu, s1z, uz * s1y)
                         + ez * __builtin_fmaf(uz, s1z, -(Bu * s1y));
        const float E0d = __builtin_fmaf(Ad, s1x, dz * s0z);
        zo[e][0] = __builtin_fmaf(nz, E0d, E01u);

        // z1 pieces
        const float E02a = RCh * __builtin_fmaf(az, s1z, -(Ba * s1y))
                         + RDh * __builtin_fmaf(Aa, s1x, az * s0z);
        const float E02b = RCh * __builtin_fmaf(bz, s1z, -(Bb * s1y))
                         + RDh * __builtin_fmaf(Ab, s1x, bz * s0z);

        const float RAg = __builtin_fmaf(gx, hx3, gy * q1t);
        const float RBg = __builtin_fmaf(gy, hx3, -(gx * q1t));
        const float RCg = gz * RDh;
        const float RDg = gz * RCh;
        const float RAe = __builtin_fmaf(ex, hx3, ey * q1t);
        const float RBe = __builtin_fmaf(ey, hx3, -(ex * q1t));
        const float RCe = ez * RDh;
        const float RDe = ez * RCh;

        const float E012b = RAg * __builtin_fmaf(bz, t01, Ab)
                          + RBg * __builtin_fmaf(Bb, s1z, bz * s1y)
                          + RCg * __builtin_fmaf(bz, s1z, -(Bb * s1y))
                          + RDg * __builtin_fmaf(Ab, s1x, bz * s0z);
        const float E012a = RAg * __builtin_fmaf(az, t01, Aa)
                          + RBg * __builtin_fmaf(Ba, s1z, az * s1y)
                          + RCg * __builtin_fmaf(az, s1z, -(Ba * s1y))
                          + RDg * __builtin_fmaf(Aa, s1x, az * s0z);
        const float E012d = RAe * __builtin_fmaf(dz, t01, Ad)
                          + RBe * __builtin_fmaf(Bd, s1z, dz * s1y)
                          + RCe * __builtin_fmaf(dz, s1z, -(Bd * s1y))
                          + RDe * __builtin_fmaf(Ad, s1x, dz * s0z);

        const float fys2x = fy * s2x;
        const float E01bf = fys2x * __builtin_fmaf(Bb, s1z, bz * s1y)
                          + fz * __builtin_fmaf(bz, s1z, -(Bb * s1y));
        const float E01af = fys2x * __builtin_fmaf(Ba, s1z, az * s1y)
                          + fz * __builtin_fmaf(az, s1z, -(Ba * s1y));

        const float E12fh = (fy * q1t) * s1x + (fy * hx3) * t0z1y
                          + (fz * RDh) * t0z1z + fz * RCh;

        const float E1g = s2x * __builtin_fmaf(gx, s1x, gy * t0z1y)
                        + gz * t0z1z;

        const float zx = __builtin_fmaf(px, E02a,
                         __builtin_fmaf(py, E012b, -(pz * E01bf)));
        const float zy = __builtin_fmaf(px, E02b,
                         __builtin_fmaf(pz, E01af, -(py * E012a)));
        const float zz = __builtin_fmaf(px, E012d,
                         __builtin_fmaf(py, E12fh, pz * E1g));
        zo[e][1] = __builtin_fmaf(nx, zx, __builtin_fmaf(ny, zy, nz * zz));
    }

    vfloat2 oa, ob;
    oa.x = __builtin_fmaf(zo[0][0], hw0, hw0);
    oa.y = __builtin_fmaf(zo[0][1], hw1, hw1);
    ob.x = __builtin_fmaf(zo[1][0], hw0, hw0);
    ob.y = __builtin_fmaf(zo[1][1], hw1, hw1);
    __builtin_nontemporal_store(oa, &out2[b]);
    __builtin_nontemporal_store(ob, &out2[b + H]);
}

extern "C" void kernel_launch(void* const* d_in, const int* in_sizes, int n_in,
                              void* d_out, int out_size, void* d_ws, size_t ws_size,
                              hipStream_t stream) {
    const float* x        = (const float*)d_in[0];
    const float* w_input  = (const float*)d_in[1];
    const float* weights  = (const float*)d_in[2];
    const float* w_output = (const float*)d_in[3];
    float* out = (float*)d_out;

    const int B = in_sizes[0] / 4;
    const int H = B >> 1;

    heaq_kernel<<<(H + 255) / 256, 256, 0, stream>>>(
        (const vfloat4*)x, w_input, weights, w_output, (vfloat2*)out, H);
}